// Round 9
// baseline (24716.747 us; speedup 1.0000x reference)
//
#include <hip/hip_runtime.h>
#include <math.h>

// ---- problem dims ----
#define TN 64
#define BN 32
#define EPSF 1e-6f

// ---- workspace layout (floats): full H/RV history for deferred out-GEMM ----
constexpr long OFF_H     = 0;                       // 65 * 32*1024
constexpr long OFF_RV    = OFF_H    + 65L*32768;    // 65 * 32*256
constexpr long OFF_S     = OFF_RV   + 65L*8192;     // 32768
constexpr long OFF_RW    = OFF_S    + 32768;        // B*N*HD = 16384
constexpr long OFF_WW    = OFF_RW   + 16384;        // B*N
constexpr long OFF_U     = OFF_WW   + 4096;
constexpr long OFF_P     = OFF_U    + 4096;
constexpr long OFF_MEM   = OFF_P    + 4096;         // B*N*WD = 262144
constexpr long OFF_LINKS = OFF_MEM  + 262144;       // B*N*N = 524288
constexpr long OFF_SRC   = OFF_LINKS+ 524288;       // 2048 ints
// total ≈ 13.7 MB

__device__ __forceinline__ float sigm(float x) { return 1.f / (1.f + expf(-x)); }
__device__ __forceinline__ float oneplus_(float x) {
  return 1.f + fmaxf(x, 0.f) + log1pf(expf(-fabsf(x)));
}

// ===== src width auto-detect + decode to int32 (validated round 6) =========
__global__ void src_decode(const void* __restrict__ src_raw, float* __restrict__ ws) {
  __shared__ int is64_s;
  if (threadIdx.x == 0) is64_s = 1;
  __syncthreads();
  const long long* s64 = (const long long*)src_raw;
  for (int i = threadIdx.x; i < 1024; i += 256) {
    long long v = s64[i];
    if (v < 0 || v >= 32000) is64_s = 0;
  }
  __syncthreads();
  int* dst = (int*)(ws + OFF_SRC);
  if (is64_s) {
    for (int i = threadIdx.x; i < 2048; i += 256) dst[i] = (int)s64[i];
  } else {
    const int* s32 = (const int*)src_raw;
    for (int i = threadIdx.x; i < 2048; i += 256) dst[i] = s32[i];
  }
}

// ================= init: H slot0, RV slot0, state; U=EPS ====================
__global__ void init_kernel(float* ws) {
  long i0 = (long)blockIdx.x * blockDim.x + threadIdx.x;
  long stride = (long)gridDim.x * blockDim.x;
  for (long x = i0; x < 32768; x += stride) ws[OFF_H + x] = 0.f;
  for (long x = i0; x < 8192;  x += stride) ws[OFF_RV + x] = 0.f;
  const long zlen = OFF_SRC - OFF_S;
  for (long x = i0; x < zlen; x += stride) {
    long g = OFF_S + x;
    ws[g] = (g >= OFF_U && g < OFF_U + 4096) ? EPSF : 0.f;
  }
}

// ===== gates4: fused gates-GEMM + LSTM pointwise (validated round 7) =======
__global__ __launch_bounds__(256) void gates4_kernel(
    int t, const float* __restrict__ emb,
    const float* __restrict__ W_ih, const float* __restrict__ W_hh,
    const float* __restrict__ b_ih, const float* __restrict__ b_hh,
    float* __restrict__ ws) {
  __shared__ float xl[32 * 260];
  int tid = threadIdx.x;
  int b = tid & 31, jg = tid >> 5;
  int j = blockIdx.x * 8 + jg;
  const int* src = (const int*)(ws + OFF_SRC);
  float acc0 = 0.f, acc1 = 0.f, acc2 = 0.f, acc3 = 0.f;
  for (int c = 0; c < 7; ++c) {
    __syncthreads();
#pragma unroll
    for (int q = 0; q < 32; ++q) {
      int i2 = q * 256 + tid;
      int bb = i2 >> 8, kk = i2 & 255;
      float v;
      if (c < 2)       v = emb[(long)src[t * 32 + bb] * 512 + c * 256 + kk];
      else if (c == 2) v = ws[OFF_RV + (long)t * 8192 + bb * 256 + kk];
      else             v = ws[OFF_H + (long)t * 32768 + bb * 1024 + (c - 3) * 256 + kk];
      xl[bb * 260 + kk] = v;
    }
    __syncthreads();
    const float* xp = &xl[b * 260];
    const float *w0, *w1, *w2, *w3;
    if (c < 3) {
      w0 = W_ih + (long)j * 768 + c * 256;
      w1 = W_ih + (long)(1024 + j) * 768 + c * 256;
      w2 = W_ih + (long)(2048 + j) * 768 + c * 256;
      w3 = W_ih + (long)(3072 + j) * 768 + c * 256;
    } else {
      w0 = W_hh + (long)j * 1024 + (c - 3) * 256;
      w1 = W_hh + (long)(1024 + j) * 1024 + (c - 3) * 256;
      w2 = W_hh + (long)(2048 + j) * 1024 + (c - 3) * 256;
      w3 = W_hh + (long)(3072 + j) * 1024 + (c - 3) * 256;
    }
#pragma unroll 4
    for (int k = 0; k < 256; k += 4) {
      float4 xv = *(const float4*)(xp + k);
      float4 a = *(const float4*)(w0 + k);
      float4 bb4 = *(const float4*)(w1 + k);
      float4 cc4 = *(const float4*)(w2 + k);
      float4 dd4 = *(const float4*)(w3 + k);
      acc0 += xv.x * a.x + xv.y * a.y + xv.z * a.z + xv.w * a.w;
      acc1 += xv.x * bb4.x + xv.y * bb4.y + xv.z * bb4.z + xv.w * bb4.w;
      acc2 += xv.x * cc4.x + xv.y * cc4.y + xv.z * cc4.z + xv.w * cc4.w;
      acc3 += xv.x * dd4.x + xv.y * dd4.y + xv.z * dd4.z + xv.w * dd4.w;
    }
  }
  float gi = acc0 + b_ih[j]        + b_hh[j];
  float gf = acc1 + b_ih[1024 + j] + b_hh[1024 + j];
  float gg = acc2 + b_ih[2048 + j] + b_hh[2048 + j];
  float go = acc3 + b_ih[3072 + j] + b_hh[3072 + j];
  long si = (long)b * 1024 + j;
  float sv = sigm(gf) * ws[OFF_S + si] + sigm(gi) * tanhf(gg);
  ws[OFF_S + si] = sv;
  ws[OFF_H + (long)(t + 1) * 32768 + si] = sigm(go) * tanhf(sv);
}

// ===== block reductions over 128 threads (LDS) =====
__device__ __forceinline__ float blk_max(float v, float* red, int n) {
  red[n] = v; __syncthreads();
#pragma unroll
  for (int s = 64; s > 0; s >>= 1) { if (n < s) red[n] = fmaxf(red[n], red[n + s]); __syncthreads(); }
  float r = red[0]; __syncthreads();
  return r;
}
__device__ __forceinline__ float blk_sum(float v, float* red, int n) {
  red[n] = v; __syncthreads();
#pragma unroll
  for (int s = 64; s > 0; s >>= 1) { if (n < s) red[n] += red[n + s]; __syncthreads(); }
  float r = red[0]; __syncthreads();
  return r;
}

// ===== memfull: proj + memA + memBC fused, one block per batch b ===========
// 32 blocks x 128 threads. LDS ~44KB: mem in padded [128][65], proj in pjl.
__global__ __launch_bounds__(128) void memfull_kernel(
    int t, float* __restrict__ ws,
    const float* rk_w, const float* rk_b, const float* rs_w, const float* rs_b,
    const float* fg_w, const float* fg_b, const float* rm_w, const float* rm_b,
    const float* wk_w, const float* wk_b, const float* ws_w, const float* ws_b,
    const float* ev_w, const float* ev_b, const float* wv_w, const float* wv_b,
    const float* ag_w, const float* ag_b, const float* wg_w, const float* wg_b) {
  __shared__ float mem_s[128 * 65];
  __shared__ float pjl[512];
  __shared__ float su[128], lg[128], red[128], wwl[128], pl[128];
  __shared__ float kwl[64], knl[64], dl[64], kl[256];
  __shared__ float rwold[512], rwnew[512];
  int b = blockIdx.x, n = threadIdx.x;
  float* u    = ws + OFF_U  + b * 128;
  float* wwp  = ws + OFF_WW + b * 128;
  float* pp   = ws + OFF_P  + b * 128;
  float* rwp  = ws + OFF_RW + b * 512;
  float* memp = ws + OFF_MEM + (long)b * 8192;
  float* lk   = ws + OFF_LINKS + (long)b * 16384;

  // ---- phase 0: proj (wave-per-output, identical math to r7 proj_kernel) --
  {
    int wv = n >> 6, lane = n & 63;
    const float* hb = ws + OFF_H + (long)(t + 1) * 32768 + b * 1024;
    for (int o = wv; o < 471; o += 2) {
      const float* w;
      float bias;
      if (o < 256)      { int wi = o >> 2, hh = o & 3; w = rk_w + (long)(hh * 64 + wi) * 1024; bias = rk_b[hh * 64 + wi]; }
      else if (o < 260) { int q = o - 256; w = rs_w + (long)q * 1024; bias = rs_b[q]; }
      else if (o < 264) { int q = o - 260; w = fg_w + (long)q * 1024; bias = fg_b[q]; }
      else if (o < 276) { int q = o - 264, m = q >> 2, hh = q & 3; w = rm_w + (long)(hh * 3 + m) * 1024; bias = rm_b[hh * 3 + m]; }
      else if (o < 340) { int q = o - 276; w = wk_w + (long)q * 1024; bias = wk_b[q]; }
      else if (o == 340){ w = ws_w; bias = ws_b[0]; }
      else if (o < 405) { int q = o - 341; w = ev_w + (long)q * 1024; bias = ev_b[q]; }
      else if (o < 469) { int q = o - 405; w = wv_w + (long)q * 1024; bias = wv_b[q]; }
      else if (o == 469){ w = ag_w; bias = ag_b[0]; }
      else              { w = wg_w; bias = wg_b[0]; }
      const float* hp = hb + lane * 16;
      const float* wp = w + lane * 16;
      float s = 0.f;
#pragma unroll
      for (int m = 0; m < 16; m += 4) {
        float4 a = *(const float4*)(hp + m);
        float4 wv4 = *(const float4*)(wp + m);
        s += a.x * wv4.x + a.y * wv4.y + a.z * wv4.z + a.w * wv4.w;
      }
#pragma unroll
      for (int off = 32; off; off >>= 1) s += __shfl_xor(s, off);
      if (lane == 0) pjl[o] = s + bias;
    }
  }
  // ---- load mem into LDS (coalesced, padded [128][65]) --------------------
  for (int q = 0; q < 64; ++q) {
    int idx = q * 128 + n;                     // 0..8191
    mem_s[(idx >> 6) * 65 + (idx & 63)] = memp[idx];
  }
  __syncthreads();

  // ================= memA logic (pjl in place of pj) ========================
  float fg0 = sigm(pjl[260]), fg1 = sigm(pjl[261]), fg2 = sigm(pjl[262]), fg3 = sigm(pjl[263]);
  float r0 = rwp[n * 4], r1 = rwp[n * 4 + 1], r2 = rwp[n * 4 + 2], r3 = rwp[n * 4 + 3];
  rwold[n * 4] = r0; rwold[n * 4 + 1] = r1; rwold[n * 4 + 2] = r2; rwold[n * 4 + 3] = r3;
  float psi = expf(logf(1.f - fg0 * r0) + logf(1.f - fg1 * r1) +
                   logf(1.f - fg2 * r2) + logf(1.f - fg3 * r3));
  float uu = u[n], wwo = wwp[n];
  uu = (uu + wwo - uu * wwo) * psi;
  u[n] = uu;
  su[n] = uu;
  if (n < 64) {
    kwl[n] = pjl[276 + n];
    dl[n] = sigm(pjl[405 + n]) - sigm(pjl[341 + n]);  // writev - erase
#pragma unroll
    for (int h = 0; h < 4; ++h) kl[n * 4 + h] = pjl[n * 4 + h];
  }
  __syncthreads();
  float kn2 = 0.f;
#pragma unroll
  for (int w = 0; w < 64; ++w) kn2 += kwl[w] * kwl[w];
  float kn = sqrtf(kn2);
  if (n < 64) knl[n] = kwl[n] / kn;
  // bitonic ascending sort
  for (int k = 2; k <= 128; k <<= 1) {
    for (int jj = k >> 1; jj > 0; jj >>= 1) {
      int ixj = n ^ jj;
      if (ixj > n) {
        float a1 = su[n], a2 = su[ixj];
        if (((n & k) == 0) ? (a1 > a2) : (a1 < a2)) { su[n] = a2; su[ixj] = a1; }
      }
      __syncthreads();
    }
  }
  // Hillis-Steele inclusive scan of logs
  lg[n] = logf(su[n]);
  __syncthreads();
  for (int off = 1; off < 128; off <<= 1) {
    float v = (n >= off) ? lg[n - off] : 0.f;
    __syncthreads();
    lg[n] += v;
    __syncthreads();
  }
  float a_n = (1.f - su[n]) * expf(lg[n] - logf(su[n]));
  // write attention (mem row from LDS)
  float mrow[64];
  float sq = 0.f;
#pragma unroll
  for (int w = 0; w < 64; ++w) { float m = mem_s[n * 65 + w]; mrow[w] = m; sq += m * m; }
  float den = sqrtf(sq) + EPSF;
#pragma unroll
  for (int w = 0; w < 64; ++w) mrow[w] = mrow[w] / den;
  float dot = 0.f;
#pragma unroll
  for (int w = 0; w < 64; ++w) dot += mrow[w] * knl[w];
  float score = dot * oneplus_(pjl[340]);
  float mx = blk_max(score, red, n);
  float e = expf(score - mx);
  float cw = e / blk_sum(e, red, n);
  float ag = sigm(pjl[469]), wg = sigm(pjl[470]);
  float wwn = wg * (ag * a_n + (1.f - ag) * cw);
  wwp[n] = wwn; wwl[n] = wwn;
  float sumww = blk_sum(wwn, red, n);
  float pn = (1.f - sumww) * pp[n] + wwn;
  pp[n] = pn; pl[n] = pn;
  __syncthreads();
  // mem = mem_norm + ww*(writev-erase) (into LDS)
#pragma unroll
  for (int w = 0; w < 64; ++w) mem_s[n * 65 + w] = mrow[w] + wwn * dl[w];
  // link update (global, thread n owns column n — round-1-validated RAW)
  for (int k2 = 0; k2 < 128; ++k2) {
    long idx = (long)k2 * 128 + n;
    float v = lk[idx] * (1.f - (wwl[k2] + wwl[n])) + wwl[k2] * pl[n];
    lk[idx] = (k2 == n) ? 0.f : v;
  }
  __syncthreads();   // links + mem_s visible

  // ================= memBC logic ============================================
  // renormalize memory (persists)
  sq = 0.f;
#pragma unroll
  for (int w = 0; w < 64; ++w) { float m = mem_s[n * 65 + w]; mrow[w] = m; sq += m * m; }
  float den2 = sqrtf(sq) + EPSF;
#pragma unroll
  for (int w = 0; w < 64; ++w) { mrow[w] = mrow[w] / den2; mem_s[n * 65 + w] = mrow[w]; }
  // read attention per head
  float cr_[4];
#pragma unroll
  for (int h = 0; h < 4; ++h) {
    float s3 = 0.f;
#pragma unroll
    for (int w = 0; w < 64; ++w) { float kv = kl[w * 4 + h]; s3 += kv * kv; }
    float knh = sqrtf(s3);
    float d2 = 0.f;
#pragma unroll
    for (int w = 0; w < 64; ++w) d2 += mrow[w] * (kl[w * 4 + h] / knh);
    float sc = d2 * oneplus_(pjl[256 + h]);
    float mxh = blk_max(sc, red, n);
    float eh = expf(sc - mxh);
    cr_[h] = eh / blk_sum(eh, red, n);
  }
  // f/b via links (global; lcol coalesced, lrow row-gather from L1/L2)
  float f0 = 0, f1 = 0, f2 = 0, f3 = 0, b0 = 0, b1 = 0, b2 = 0, b3 = 0;
  for (int jj = 0; jj < 128; ++jj) {
    float lrow = lk[(long)n * 128 + jj];
    float lcol = lk[(long)jj * 128 + n];
    float q0 = rwold[jj * 4], q1 = rwold[jj * 4 + 1], q2 = rwold[jj * 4 + 2], q3 = rwold[jj * 4 + 3];
    f0 += lrow * q0; f1 += lrow * q1; f2 += lrow * q2; f3 += lrow * q3;
    b0 += lcol * q0; b1 += lcol * q1; b2 += lcol * q2; b3 += lcol * q3;
  }
  float fv[4] = {f0, f1, f2, f3}, bv[4] = {b0, b1, b2, b3};
#pragma unroll
  for (int h = 0; h < 4; ++h) {
    float m0 = pjl[264 + h], m1 = pjl[264 + 4 + h], m2 = pjl[264 + 8 + h];
    float mm = fmaxf(m0, fmaxf(m1, m2));
    float e0 = expf(m0 - mm), e1 = expf(m1 - mm), e2 = expf(m2 - mm);
    float inv = 1.f / (e0 + e1 + e2);
    float rwv = (e0 * inv) * bv[h] + (e1 * inv) * cr_[h] + (e2 * inv) * fv[h];
    rwp[n * 4 + h] = rwv;
    rwnew[n * 4 + h] = rwv;
  }
  __syncthreads();
  // write mem back to global (coalesced)
  for (int q = 0; q < 64; ++q) {
    int idx = q * 128 + n;
    memp[idx] = mem_s[(idx >> 6) * 65 + (idx & 63)];
  }
  // rv = mem^T @ rw_new (from LDS)
  int w2 = n & 63, which = n >> 6;
  float rv0 = 0.f, rv1 = 0.f;
  for (int jj = 0; jj < 128; ++jj) {
    float mv = mem_s[jj * 65 + w2];
    rv0 += mv * rwnew[jj * 4 + which * 2];
    rv1 += mv * rwnew[jj * 4 + which * 2 + 1];
  }
  float* RVp = ws + OFF_RV + (long)(t + 1) * 8192 + b * 256;
  RVp[w2 * 4 + which * 2]     = rv0;
  RVp[w2 * 4 + which * 2 + 1] = rv1;
}

// ===== final output GEMM: [2048,16000], K=1280, fp32 out (r7 validated) ====
__global__ __launch_bounds__(256) void out_gemm(
    const float* __restrict__ ws, const float* __restrict__ Why_w,
    const float* __restrict__ Why_b, const float* __restrict__ Wry_w,
    float* __restrict__ out) {
  __shared__ float al[16 * 132];
  __shared__ float bl[16 * 132];
  const float* Hp  = ws + OFF_H + 32768;   // [2048][1024]
  const float* RVp = ws + OFF_RV + 8192;   // [2048][256]
  int tid = threadIdx.x;
  int tx = tid & 15, ty = tid >> 4;
  int col0 = blockIdx.x * 128, row0 = blockIdx.y * 128;
  float acc[8][8];
#pragma unroll
  for (int i = 0; i < 8; ++i)
#pragma unroll
    for (int j = 0; j < 8; ++j) acc[i][j] = 0.f;
  for (int kt = 0; kt < 80; ++kt) {
    int k0 = kt * 16;
    __syncthreads();
#pragma unroll
    for (int q = 0; q < 8; ++q) {
      int i2 = q * 256 + tid;
      int r = i2 >> 4, k = i2 & 15;
      int gk = k0 + k;
      float va = (gk < 1024) ? Hp[(long)(row0 + r) * 1024 + gk]
                             : RVp[(long)(row0 + r) * 256 + gk - 1024];
      al[k * 132 + r] = va;
      float vb = (gk < 1024) ? Why_w[(long)(col0 + r) * 1024 + gk]
                             : Wry_w[(long)(col0 + r) * 256 + gk - 1024];
      bl[k * 132 + r] = vb;
    }
    __syncthreads();
#pragma unroll
    for (int k = 0; k < 16; ++k) {
      float4 a0 = *(const float4*)&al[k * 132 + ty * 8];
      float4 a1 = *(const float4*)&al[k * 132 + ty * 8 + 4];
      float4 c0 = *(const float4*)&bl[k * 132 + tx * 8];
      float4 c1 = *(const float4*)&bl[k * 132 + tx * 8 + 4];
      float ar[8] = {a0.x, a0.y, a0.z, a0.w, a1.x, a1.y, a1.z, a1.w};
      float br[8] = {c0.x, c0.y, c0.z, c0.w, c1.x, c1.y, c1.z, c1.w};
#pragma unroll
      for (int i = 0; i < 8; ++i)
#pragma unroll
        for (int j = 0; j < 8; ++j) acc[i][j] += ar[i] * br[j];
    }
  }
  float4 bb0 = *(const float4*)&Why_b[col0 + tx * 8];
  float4 bb1 = *(const float4*)&Why_b[col0 + tx * 8 + 4];
  float bias[8] = {bb0.x, bb0.y, bb0.z, bb0.w, bb1.x, bb1.y, bb1.z, bb1.w};
#pragma unroll
  for (int i = 0; i < 8; ++i) {
    long r = row0 + ty * 8 + i;
    float* op = out + r * 16000 + col0 + tx * 8;
    float4 o0 = {acc[i][0] + bias[0], acc[i][1] + bias[1], acc[i][2] + bias[2], acc[i][3] + bias[3]};
    float4 o1 = {acc[i][4] + bias[4], acc[i][5] + bias[5], acc[i][6] + bias[6], acc[i][7] + bias[7]};
    *(float4*)op = o0;
    *(float4*)(op + 4) = o1;
  }
}

extern "C" void kernel_launch(void* const* d_in, const int* in_sizes, int n_in,
                              void* d_out, int out_size, void* d_ws, size_t ws_size,
                              hipStream_t stream) {
  const void* src_raw = d_in[0];
  const float* emb   = (const float*)d_in[1];
  const float* W_ih  = (const float*)d_in[2];
  const float* W_hh  = (const float*)d_in[3];
  const float* b_ih  = (const float*)d_in[4];
  const float* b_hh  = (const float*)d_in[5];
  const float* rk_w  = (const float*)d_in[6];
  const float* rk_b  = (const float*)d_in[7];
  const float* rs_w  = (const float*)d_in[8];
  const float* rs_b  = (const float*)d_in[9];
  const float* fg_w  = (const float*)d_in[10];
  const float* fg_b  = (const float*)d_in[11];
  const float* rm_w  = (const float*)d_in[12];
  const float* rm_b  = (const float*)d_in[13];
  const float* wk_w  = (const float*)d_in[14];
  const float* wk_b  = (const float*)d_in[15];
  const float* ws_w  = (const float*)d_in[16];
  const float* ws_b  = (const float*)d_in[17];
  const float* ev_w  = (const float*)d_in[18];
  const float* ev_b  = (const float*)d_in[19];
  const float* wv_w  = (const float*)d_in[20];
  const float* wv_b  = (const float*)d_in[21];
  const float* ag_w  = (const float*)d_in[22];
  const float* ag_b  = (const float*)d_in[23];
  const float* wg_w  = (const float*)d_in[24];
  const float* wg_b  = (const float*)d_in[25];
  const float* Why_w = (const float*)d_in[26];
  const float* Why_b = (const float*)d_in[27];
  const float* Wry_w = (const float*)d_in[28];
  float* ws = (float*)d_ws;
  float* out = (float*)d_out;

  src_decode<<<1, 256, 0, stream>>>(src_raw, ws);
  init_kernel<<<512, 256, 0, stream>>>(ws);
  for (int t = 0; t < TN; ++t) {
    gates4_kernel<<<128, 256, 0, stream>>>(t, emb, W_ih, W_hh, b_ih, b_hh, ws);
    memfull_kernel<<<32, 128, 0, stream>>>(t, ws, rk_w, rk_b, rs_w, rs_b, fg_w, fg_b,
                                           rm_w, rm_b, wk_w, wk_b, ws_w, ws_b,
                                           ev_w, ev_b, wv_w, wv_b, ag_w, ag_b, wg_w, wg_b);
  }
  out_gemm<<<dim3(125, 16), 256, 0, stream>>>(ws, Why_w, Why_b, Wry_w, out);
}

// Round 10
// 18169.202 us; speedup vs baseline: 1.3604x; 1.3604x over previous
//
#include <hip/hip_runtime.h>
#include <math.h>

// ---- problem dims ----
#define TN 64
#define BN 32
#define EPSF 1e-6f

// ---- workspace layout (floats): full H/RV history for deferred out-GEMM ----
constexpr long OFF_H     = 0;                       // 65 * 32*1024
constexpr long OFF_RV    = OFF_H    + 65L*32768;    // 65 * 32*256
constexpr long OFF_S     = OFF_RV   + 65L*8192;     // 32768
constexpr long OFF_RW    = OFF_S    + 32768;        // B*N*HD = 16384
constexpr long OFF_WW    = OFF_RW   + 16384;        // B*N
constexpr long OFF_U     = OFF_WW   + 4096;
constexpr long OFF_P     = OFF_U    + 4096;
constexpr long OFF_MEM   = OFF_P    + 4096;         // B*N*WD = 262144
constexpr long OFF_LINKS = OFF_MEM  + 262144;       // B*N*N = 524288
constexpr long OFF_PROJ  = OFF_LINKS+ 524288;       // B*512 (471 used)
constexpr long OFF_SRC   = OFF_PROJ + 16384;        // 2048 ints
// total ≈ 14.1 MB (r7 footprint, proven)

__device__ __forceinline__ float sigm(float x) { return 1.f / (1.f + expf(-x)); }
__device__ __forceinline__ float oneplus_(float x) {
  return 1.f + fmaxf(x, 0.f) + log1pf(expf(-fabsf(x)));
}

// ===== src width auto-detect + decode to int32 (validated round 6) =========
__global__ void src_decode(const void* __restrict__ src_raw, float* __restrict__ ws) {
  __shared__ int is64_s;
  if (threadIdx.x == 0) is64_s = 1;
  __syncthreads();
  const long long* s64 = (const long long*)src_raw;
  for (int i = threadIdx.x; i < 1024; i += 256) {
    long long v = s64[i];
    if (v < 0 || v >= 32000) is64_s = 0;
  }
  __syncthreads();
  int* dst = (int*)(ws + OFF_SRC);
  if (is64_s) {
    for (int i = threadIdx.x; i < 2048; i += 256) dst[i] = (int)s64[i];
  } else {
    const int* s32 = (const int*)src_raw;
    for (int i = threadIdx.x; i < 2048; i += 256) dst[i] = s32[i];
  }
}

// ================= init: H slot0, RV slot0, state; U=EPS ====================
__global__ void init_kernel(float* ws) {
  long i0 = (long)blockIdx.x * blockDim.x + threadIdx.x;
  long stride = (long)gridDim.x * blockDim.x;
  for (long x = i0; x < 32768; x += stride) ws[OFF_H + x] = 0.f;
  for (long x = i0; x < 8192;  x += stride) ws[OFF_RV + x] = 0.f;
  const long zlen = OFF_PROJ - OFF_S;
  for (long x = i0; x < zlen; x += stride) {
    long g = OFF_S + x;
    ws[g] = (g >= OFF_U && g < OFF_U + 4096) ? EPSF : 0.f;
  }
}

// ===== gates4: fused gates-GEMM + LSTM pointwise; 256 blocks x 128 thr =====
// thread: b = tid&31, jg = tid>>5 (0..3); j = blk*4 + jg (0..1023)
__global__ __launch_bounds__(128) void gates4_kernel(
    int t, const float* __restrict__ emb,
    const float* __restrict__ W_ih, const float* __restrict__ W_hh,
    const float* __restrict__ b_ih, const float* __restrict__ b_hh,
    float* __restrict__ ws) {
  __shared__ float xl[32 * 260];
  int tid = threadIdx.x;
  int b = tid & 31, jg = tid >> 5;
  int j = blockIdx.x * 4 + jg;
  const int* src = (const int*)(ws + OFF_SRC);
  float acc0 = 0.f, acc1 = 0.f, acc2 = 0.f, acc3 = 0.f;
  for (int c = 0; c < 7; ++c) {
    __syncthreads();
#pragma unroll
    for (int q = 0; q < 64; ++q) {
      int i2 = q * 128 + tid;
      int bb = i2 >> 8, kk = i2 & 255;
      float v;
      if (c < 2)       v = emb[(long)src[t * 32 + bb] * 512 + c * 256 + kk];
      else if (c == 2) v = ws[OFF_RV + (long)t * 8192 + bb * 256 + kk];
      else             v = ws[OFF_H + (long)t * 32768 + bb * 1024 + (c - 3) * 256 + kk];
      xl[bb * 260 + kk] = v;
    }
    __syncthreads();
    const float* xp = &xl[b * 260];
    const float *w0, *w1, *w2, *w3;
    if (c < 3) {
      w0 = W_ih + (long)j * 768 + c * 256;
      w1 = W_ih + (long)(1024 + j) * 768 + c * 256;
      w2 = W_ih + (long)(2048 + j) * 768 + c * 256;
      w3 = W_ih + (long)(3072 + j) * 768 + c * 256;
    } else {
      w0 = W_hh + (long)j * 1024 + (c - 3) * 256;
      w1 = W_hh + (long)(1024 + j) * 1024 + (c - 3) * 256;
      w2 = W_hh + (long)(2048 + j) * 1024 + (c - 3) * 256;
      w3 = W_hh + (long)(3072 + j) * 1024 + (c - 3) * 256;
    }
#pragma unroll 4
    for (int k = 0; k < 256; k += 4) {
      float4 xv = *(const float4*)(xp + k);
      float4 a = *(const float4*)(w0 + k);
      float4 bb4 = *(const float4*)(w1 + k);
      float4 cc4 = *(const float4*)(w2 + k);
      float4 dd4 = *(const float4*)(w3 + k);
      acc0 += xv.x * a.x + xv.y * a.y + xv.z * a.z + xv.w * a.w;
      acc1 += xv.x * bb4.x + xv.y * bb4.y + xv.z * bb4.z + xv.w * bb4.w;
      acc2 += xv.x * cc4.x + xv.y * cc4.y + xv.z * cc4.z + xv.w * cc4.w;
      acc3 += xv.x * dd4.x + xv.y * dd4.y + xv.z * dd4.z + xv.w * dd4.w;
    }
  }
  float gi = acc0 + b_ih[j]        + b_hh[j];
  float gf = acc1 + b_ih[1024 + j] + b_hh[1024 + j];
  float gg = acc2 + b_ih[2048 + j] + b_hh[2048 + j];
  float go = acc3 + b_ih[3072 + j] + b_hh[3072 + j];
  long si = (long)b * 1024 + j;
  float sv = sigm(gf) * ws[OFF_S + si] + sigm(gi) * tanhf(gg);
  ws[OFF_S + si] = sv;
  ws[OFF_H + (long)(t + 1) * 32768 + si] = sigm(go) * tanhf(sv);
}

// ===== proj: wave-per-output, float4 loads + shfl_xor (r7 validated) =======
__global__ __launch_bounds__(256) void proj_kernel(
    int t, float* __restrict__ ws,
    const float* rk_w, const float* rk_b, const float* rs_w, const float* rs_b,
    const float* fg_w, const float* fg_b, const float* rm_w, const float* rm_b,
    const float* wk_w, const float* wk_b, const float* ws_w, const float* ws_b,
    const float* ev_w, const float* ev_b, const float* wv_w, const float* wv_b,
    const float* ag_w, const float* ag_b, const float* wg_w, const float* wg_b) {
  int wid = blockIdx.x * 4 + (threadIdx.x >> 6);  // 0..15071
  int lane = threadIdx.x & 63;
  int o = wid >> 5, b = wid & 31;
  const float* w;
  float bias;
  if (o < 256)      { int wi = o >> 2, hh = o & 3; w = rk_w + (long)(hh * 64 + wi) * 1024; bias = rk_b[hh * 64 + wi]; }
  else if (o < 260) { int q = o - 256; w = rs_w + (long)q * 1024; bias = rs_b[q]; }
  else if (o < 264) { int q = o - 260; w = fg_w + (long)q * 1024; bias = fg_b[q]; }
  else if (o < 276) { int q = o - 264, m = q >> 2, hh = q & 3; w = rm_w + (long)(hh * 3 + m) * 1024; bias = rm_b[hh * 3 + m]; }
  else if (o < 340) { int q = o - 276; w = wk_w + (long)q * 1024; bias = wk_b[q]; }
  else if (o == 340){ w = ws_w; bias = ws_b[0]; }
  else if (o < 405) { int q = o - 341; w = ev_w + (long)q * 1024; bias = ev_b[q]; }
  else if (o < 469) { int q = o - 405; w = wv_w + (long)q * 1024; bias = wv_b[q]; }
  else if (o == 469){ w = ag_w; bias = ag_b[0]; }
  else              { w = wg_w; bias = wg_b[0]; }
  const float* hp = ws + OFF_H + (long)(t + 1) * 32768 + b * 1024 + lane * 16;
  const float* wp = w + lane * 16;
  float s = 0.f;
#pragma unroll
  for (int m = 0; m < 16; m += 4) {
    float4 a = *(const float4*)(hp + m);
    float4 wv = *(const float4*)(wp + m);
    s += a.x * wv.x + a.y * wv.y + a.z * wv.z + a.w * wv.w;
  }
#pragma unroll
  for (int off = 32; off; off >>= 1) s += __shfl_xor(s, off);
  if (lane == 0) ws[OFF_PROJ + b * 512 + o] = s + bias;
}

// ===== block reductions over 128 threads (LDS) =====
__device__ __forceinline__ float blk_max(float v, float* red, int n) {
  red[n] = v; __syncthreads();
#pragma unroll
  for (int s = 64; s > 0; s >>= 1) { if (n < s) red[n] = fmaxf(red[n], red[n + s]); __syncthreads(); }
  float r = red[0]; __syncthreads();
  return r;
}
__device__ __forceinline__ float blk_sum(float v, float* red, int n) {
  red[n] = v; __syncthreads();
#pragma unroll
  for (int s = 64; s > 0; s >>= 1) { if (n < s) red[n] += red[n + s]; __syncthreads(); }
  float r = red[0]; __syncthreads();
  return r;
}

// ===== memAB: memA + memBC fused; mem AND links in dynamic LDS (105 KB) ====
// 32 blocks x 128 threads. LDS: mem_s [128][65], lk_s [128][129], small arrays.
constexpr int SMEM_FLOATS = 128 * 65 + 128 * 129 + 5 * 128 + 3 * 64 + 256 + 512 + 512;
__global__ __launch_bounds__(128) void memAB_kernel(int t, float* __restrict__ ws) {
  extern __shared__ float sm[];
  float* mem_s = sm;                    // 8320
  float* lk_s  = sm + 8320;             // 16512 (pad 129)
  float* su    = sm + 24832;
  float* lg    = su + 128;
  float* red   = lg + 128;
  float* wwl   = red + 128;
  float* pl    = wwl + 128;
  float* kwl   = pl + 128;              // 64
  float* knl   = kwl + 64;              // 64
  float* dl    = knl + 64;              // 64
  float* kl    = dl + 64;               // 256
  float* rwold = kl + 256;              // 512
  float* rwnew = rwold + 512;           // 512
  int b = blockIdx.x, n = threadIdx.x;
  const float* pj = ws + OFF_PROJ + b * 512;
  float* u    = ws + OFF_U  + b * 128;
  float* wwp  = ws + OFF_WW + b * 128;
  float* pp   = ws + OFF_P  + b * 128;
  float* rwp  = ws + OFF_RW + b * 512;
  float* memp = ws + OFF_MEM + (long)b * 8192;
  float* lk   = ws + OFF_LINKS + (long)b * 16384;

  // ---- load mem + links into LDS (coalesced) ------------------------------
  for (int q = 0; q < 64; ++q) {
    int idx = q * 128 + n;
    mem_s[(idx >> 6) * 65 + (idx & 63)] = memp[idx];
  }
  for (int q = 0; q < 128; ++q) lk_s[q * 129 + n] = lk[q * 128 + n];

  // ================= memA ===================================================
  float fg0 = sigm(pj[260]), fg1 = sigm(pj[261]), fg2 = sigm(pj[262]), fg3 = sigm(pj[263]);
  float r0 = rwp[n * 4], r1 = rwp[n * 4 + 1], r2 = rwp[n * 4 + 2], r3 = rwp[n * 4 + 3];
  rwold[n * 4] = r0; rwold[n * 4 + 1] = r1; rwold[n * 4 + 2] = r2; rwold[n * 4 + 3] = r3;
  float psi = expf(logf(1.f - fg0 * r0) + logf(1.f - fg1 * r1) +
                   logf(1.f - fg2 * r2) + logf(1.f - fg3 * r3));
  float uu = u[n], wwo = wwp[n];
  uu = (uu + wwo - uu * wwo) * psi;
  u[n] = uu;
  su[n] = uu;
  if (n < 64) {
    kwl[n] = pj[276 + n];
    dl[n] = sigm(pj[405 + n]) - sigm(pj[341 + n]);  // writev - erase
#pragma unroll
    for (int h = 0; h < 4; ++h) kl[n * 4 + h] = pj[n * 4 + h];
  }
  __syncthreads();
  float kn2 = 0.f;
#pragma unroll
  for (int w = 0; w < 64; ++w) kn2 += kwl[w] * kwl[w];
  float kn = sqrtf(kn2);
  if (n < 64) knl[n] = kwl[n] / kn;
  // bitonic ascending sort
  for (int k = 2; k <= 128; k <<= 1) {
    for (int jj = k >> 1; jj > 0; jj >>= 1) {
      int ixj = n ^ jj;
      if (ixj > n) {
        float a1 = su[n], a2 = su[ixj];
        if (((n & k) == 0) ? (a1 > a2) : (a1 < a2)) { su[n] = a2; su[ixj] = a1; }
      }
      __syncthreads();
    }
  }
  // Hillis-Steele inclusive scan of logs
  lg[n] = logf(su[n]);
  __syncthreads();
  for (int off = 1; off < 128; off <<= 1) {
    float v = (n >= off) ? lg[n - off] : 0.f;
    __syncthreads();
    lg[n] += v;
    __syncthreads();
  }
  float a_n = (1.f - su[n]) * expf(lg[n] - logf(su[n]));
  // write attention (mem row from LDS)
  float mrow[64];
  float sq = 0.f;
#pragma unroll
  for (int w = 0; w < 64; ++w) { float m = mem_s[n * 65 + w]; mrow[w] = m; sq += m * m; }
  float den = sqrtf(sq) + EPSF;
#pragma unroll
  for (int w = 0; w < 64; ++w) mrow[w] = mrow[w] / den;
  float dot = 0.f;
#pragma unroll
  for (int w = 0; w < 64; ++w) dot += mrow[w] * knl[w];
  float score = dot * oneplus_(pj[340]);
  float mx = blk_max(score, red, n);
  float e = expf(score - mx);
  float cw = e / blk_sum(e, red, n);
  float ag = sigm(pj[469]), wg = sigm(pj[470]);
  float wwn = wg * (ag * a_n + (1.f - ag) * cw);
  wwp[n] = wwn; wwl[n] = wwn;
  float sumww = blk_sum(wwn, red, n);
  float pn = (1.f - sumww) * pp[n] + wwn;
  pp[n] = pn; pl[n] = pn;
  __syncthreads();
  // mem = mem_norm + ww*(writev-erase)
#pragma unroll
  for (int w = 0; w < 64; ++w) mem_s[n * 65 + w] = mrow[w] + wwn * dl[w];
  // link update in LDS (thread n owns column n)
  for (int k2 = 0; k2 < 128; ++k2) {
    float v = lk_s[k2 * 129 + n] * (1.f - (wwl[k2] + wwl[n])) + wwl[k2] * pl[n];
    lk_s[k2 * 129 + n] = (k2 == n) ? 0.f : v;
  }
  __syncthreads();   // links + mem_s visible

  // ================= memBC ==================================================
  // renormalize memory (persists)
  sq = 0.f;
#pragma unroll
  for (int w = 0; w < 64; ++w) { float m = mem_s[n * 65 + w]; mrow[w] = m; sq += m * m; }
  float den2 = sqrtf(sq) + EPSF;
#pragma unroll
  for (int w = 0; w < 64; ++w) { mrow[w] = mrow[w] / den2; mem_s[n * 65 + w] = mrow[w]; }
  // read attention per head
  float cr_[4];
#pragma unroll
  for (int h = 0; h < 4; ++h) {
    float s3 = 0.f;
#pragma unroll
    for (int w = 0; w < 64; ++w) { float kv = kl[w * 4 + h]; s3 += kv * kv; }
    float knh = sqrtf(s3);
    float d2 = 0.f;
#pragma unroll
    for (int w = 0; w < 64; ++w) d2 += mrow[w] * (kl[w * 4 + h] / knh);
    float sc = d2 * oneplus_(pj[256 + h]);
    float mxh = blk_max(sc, red, n);
    float eh = expf(sc - mxh);
    cr_[h] = eh / blk_sum(eh, red, n);
  }
  // f/b via links in LDS: row stride 129 -> bank (n+jj)%32, 2-way = free
  float f0 = 0, f1 = 0, f2 = 0, f3 = 0, b0 = 0, b1 = 0, b2 = 0, b3 = 0;
  for (int jj = 0; jj < 128; ++jj) {
    float lrow = lk_s[n * 129 + jj];
    float lcol = lk_s[jj * 129 + n];
    float q0 = rwold[jj * 4], q1 = rwold[jj * 4 + 1], q2 = rwold[jj * 4 + 2], q3 = rwold[jj * 4 + 3];
    f0 += lrow * q0; f1 += lrow * q1; f2 += lrow * q2; f3 += lrow * q3;
    b0 += lcol * q0; b1 += lcol * q1; b2 += lcol * q2; b3 += lcol * q3;
  }
  float fv[4] = {f0, f1, f2, f3}, bv[4] = {b0, b1, b2, b3};
#pragma unroll
  for (int h = 0; h < 4; ++h) {
    float m0 = pj[264 + h], m1 = pj[264 + 4 + h], m2 = pj[264 + 8 + h];
    float mm = fmaxf(m0, fmaxf(m1, m2));
    float e0 = expf(m0 - mm), e1 = expf(m1 - mm), e2 = expf(m2 - mm);
    float inv = 1.f / (e0 + e1 + e2);
    float rwv = (e0 * inv) * bv[h] + (e1 * inv) * cr_[h] + (e2 * inv) * fv[h];
    rwp[n * 4 + h] = rwv;
    rwnew[n * 4 + h] = rwv;
  }
  __syncthreads();
  // store mem + links back to global (coalesced)
  for (int q = 0; q < 64; ++q) {
    int idx = q * 128 + n;
    memp[idx] = mem_s[(idx >> 6) * 65 + (idx & 63)];
  }
  for (int q = 0; q < 128; ++q) lk[q * 128 + n] = lk_s[q * 129 + n];
  // rv = mem^T @ rw_new (from LDS)
  int w2 = n & 63, which = n >> 6;
  float rv0 = 0.f, rv1 = 0.f;
  for (int jj = 0; jj < 128; ++jj) {
    float mv = mem_s[jj * 65 + w2];
    rv0 += mv * rwnew[jj * 4 + which * 2];
    rv1 += mv * rwnew[jj * 4 + which * 2 + 1];
  }
  float* RVp = ws + OFF_RV + (long)(t + 1) * 8192 + b * 256;
  RVp[w2 * 4 + which * 2]     = rv0;
  RVp[w2 * 4 + which * 2 + 1] = rv1;
}

// ===== final output GEMM: [2048,16000], K=1280, fp32 out (r7 validated) ====
__global__ __launch_bounds__(256) void out_gemm(
    const float* __restrict__ ws, const float* __restrict__ Why_w,
    const float* __restrict__ Why_b, const float* __restrict__ Wry_w,
    float* __restrict__ out) {
  __shared__ float al[16 * 132];
  __shared__ float bl[16 * 132];
  const float* Hp  = ws + OFF_H + 32768;   // [2048][1024]
  const float* RVp = ws + OFF_RV + 8192;   // [2048][256]
  int tid = threadIdx.x;
  int tx = tid & 15, ty = tid >> 4;
  int col0 = blockIdx.x * 128, row0 = blockIdx.y * 128;
  float acc[8][8];
#pragma unroll
  for (int i = 0; i < 8; ++i)
#pragma unroll
    for (int j = 0; j < 8; ++j) acc[i][j] = 0.f;
  for (int kt = 0; kt < 80; ++kt) {
    int k0 = kt * 16;
    __syncthreads();
#pragma unroll
    for (int q = 0; q < 8; ++q) {
      int i2 = q * 256 + tid;
      int r = i2 >> 4, k = i2 & 15;
      int gk = k0 + k;
      float va = (gk < 1024) ? Hp[(long)(row0 + r) * 1024 + gk]
                             : RVp[(long)(row0 + r) * 256 + gk - 1024];
      al[k * 132 + r] = va;
      float vb = (gk < 1024) ? Why_w[(long)(col0 + r) * 1024 + gk]
                             : Wry_w[(long)(col0 + r) * 256 + gk - 1024];
      bl[k * 132 + r] = vb;
    }
    __syncthreads();
#pragma unroll
    for (int k = 0; k < 16; ++k) {
      float4 a0 = *(const float4*)&al[k * 132 + ty * 8];
      float4 a1 = *(const float4*)&al[k * 132 + ty * 8 + 4];
      float4 c0 = *(const float4*)&bl[k * 132 + tx * 8];
      float4 c1 = *(const float4*)&bl[k * 132 + tx * 8 + 4];
      float ar[8] = {a0.x, a0.y, a0.z, a0.w, a1.x, a1.y, a1.z, a1.w};
      float br[8] = {c0.x, c0.y, c0.z, c0.w, c1.x, c1.y, c1.z, c1.w};
#pragma unroll
      for (int i = 0; i < 8; ++i)
#pragma unroll
        for (int j = 0; j < 8; ++j) acc[i][j] += ar[i] * br[j];
    }
  }
  float4 bb0 = *(const float4*)&Why_b[col0 + tx * 8];
  float4 bb1 = *(const float4*)&Why_b[col0 + tx * 8 + 4];
  float bias[8] = {bb0.x, bb0.y, bb0.z, bb0.w, bb1.x, bb1.y, bb1.z, bb1.w};
#pragma unroll
  for (int i = 0; i < 8; ++i) {
    long r = row0 + ty * 8 + i;
    float* op = out + r * 16000 + col0 + tx * 8;
    float4 o0 = {acc[i][0] + bias[0], acc[i][1] + bias[1], acc[i][2] + bias[2], acc[i][3] + bias[3]};
    float4 o1 = {acc[i][4] + bias[4], acc[i][5] + bias[5], acc[i][6] + bias[6], acc[i][7] + bias[7]};
    *(float4*)op = o0;
    *(float4*)(op + 4) = o1;
  }
}

extern "C" void kernel_launch(void* const* d_in, const int* in_sizes, int n_in,
                              void* d_out, int out_size, void* d_ws, size_t ws_size,
                              hipStream_t stream) {
  const void* src_raw = d_in[0];
  const float* emb   = (const float*)d_in[1];
  const float* W_ih  = (const float*)d_in[2];
  const float* W_hh  = (const float*)d_in[3];
  const float* b_ih  = (const float*)d_in[4];
  const float* b_hh  = (const float*)d_in[5];
  const float* rk_w  = (const float*)d_in[6];
  const float* rk_b  = (const float*)d_in[7];
  const float* rs_w  = (const float*)d_in[8];
  const float* rs_b  = (const float*)d_in[9];
  const float* fg_w  = (const float*)d_in[10];
  const float* fg_b  = (const float*)d_in[11];
  const float* rm_w  = (const float*)d_in[12];
  const float* rm_b  = (const float*)d_in[13];
  const float* wk_w  = (const float*)d_in[14];
  const float* wk_b  = (const float*)d_in[15];
  const float* ws_w  = (const float*)d_in[16];
  const float* ws_b  = (const float*)d_in[17];
  const float* ev_w  = (const float*)d_in[18];
  const float* ev_b  = (const float*)d_in[19];
  const float* wv_w  = (const float*)d_in[20];
  const float* wv_b  = (const float*)d_in[21];
  const float* ag_w  = (const float*)d_in[22];
  const float* ag_b  = (const float*)d_in[23];
  const float* wg_w  = (const float*)d_in[24];
  const float* wg_b  = (const float*)d_in[25];
  const float* Why_w = (const float*)d_in[26];
  const float* Why_b = (const float*)d_in[27];
  const float* Wry_w = (const float*)d_in[28];
  float* ws = (float*)d_ws;
  float* out = (float*)d_out;

  src_decode<<<1, 256, 0, stream>>>(src_raw, ws);
  init_kernel<<<512, 256, 0, stream>>>(ws);
  const size_t smem_bytes = (size_t)SMEM_FLOATS * sizeof(float);  // ~105 KB
  for (int t = 0; t < TN; ++t) {
    gates4_kernel<<<256, 128, 0, stream>>>(t, emb, W_ih, W_hh, b_ih, b_hh, ws);
    proj_kernel<<<3768, 256, 0, stream>>>(t, ws, rk_w, rk_b, rs_w, rs_b, fg_w, fg_b,
                                          rm_w, rm_b, wk_w, wk_b, ws_w, ws_b,
                                          ev_w, ev_b, wv_w, wv_b, ag_w, ag_b, wg_w, wg_b);
    memAB_kernel<<<32, 128, smem_bytes, stream>>>(t, ws);
  }
  out_gemm<<<dim3(125, 16), 256, 0, stream>>>(ws, Why_w, Why_b, Wry_w, out);
}

// Round 11
// 14421.011 us; speedup vs baseline: 1.7139x; 1.2599x over previous
//
#include <hip/hip_runtime.h>
#include <math.h>

// ---- problem dims ----
#define TN 64
#define BN 32
#define EPSF 1e-6f

// ---- workspace layout (floats): full H/RV history for deferred out-GEMM ----
constexpr long OFF_H     = 0;                       // 65 * 32*1024
constexpr long OFF_RV    = OFF_H    + 65L*32768;    // 65 * 32*256
constexpr long OFF_S     = OFF_RV   + 65L*8192;     // 32768
constexpr long OFF_RW    = OFF_S    + 32768;        // B*N*HD = 16384
constexpr long OFF_WW    = OFF_RW   + 16384;        // B*N
constexpr long OFF_U     = OFF_WW   + 4096;
constexpr long OFF_P     = OFF_U    + 4096;
constexpr long OFF_MEM   = OFF_P    + 4096;         // B*N*WD = 262144
constexpr long OFF_LINKS = OFF_MEM  + 262144;       // B*N*N = 524288
constexpr long OFF_PROJ  = OFF_LINKS+ 524288;       // B*512 (471 used)
constexpr long OFF_SRC   = OFF_PROJ + 16384;        // 2048 ints
// total ≈ 14.1 MB (r7 footprint, proven)

__device__ __forceinline__ float sigm(float x) { return 1.f / (1.f + expf(-x)); }
__device__ __forceinline__ float oneplus_(float x) {
  return 1.f + fmaxf(x, 0.f) + log1pf(expf(-fabsf(x)));
}

// ===== src width auto-detect + decode to int32 (validated round 6) =========
__global__ void src_decode(const void* __restrict__ src_raw, float* __restrict__ ws) {
  __shared__ int is64_s;
  if (threadIdx.x == 0) is64_s = 1;
  __syncthreads();
  const long long* s64 = (const long long*)src_raw;
  for (int i = threadIdx.x; i < 1024; i += 256) {
    long long v = s64[i];
    if (v < 0 || v >= 32000) is64_s = 0;
  }
  __syncthreads();
  int* dst = (int*)(ws + OFF_SRC);
  if (is64_s) {
    for (int i = threadIdx.x; i < 2048; i += 256) dst[i] = (int)s64[i];
  } else {
    const int* s32 = (const int*)src_raw;
    for (int i = threadIdx.x; i < 2048; i += 256) dst[i] = s32[i];
  }
}

// ================= init: H slot0, RV slot0, state; U=EPS ====================
__global__ void init_kernel(float* ws) {
  long i0 = (long)blockIdx.x * blockDim.x + threadIdx.x;
  long stride = (long)gridDim.x * blockDim.x;
  for (long x = i0; x < 32768; x += stride) ws[OFF_H + x] = 0.f;
  for (long x = i0; x < 8192;  x += stride) ws[OFF_RV + x] = 0.f;
  const long zlen = OFF_PROJ - OFF_S;
  for (long x = i0; x < zlen; x += stride) {
    long g = OFF_S + x;
    ws[g] = (g >= OFF_U && g < OFF_U + 4096) ? EPSF : 0.f;
  }
}

// ===== gates4: fused gates-GEMM + LSTM pointwise (r7 exact: 128 blk x 256) =
__global__ __launch_bounds__(256) void gates4_kernel(
    int t, const float* __restrict__ emb,
    const float* __restrict__ W_ih, const float* __restrict__ W_hh,
    const float* __restrict__ b_ih, const float* __restrict__ b_hh,
    float* __restrict__ ws) {
  __shared__ float xl[32 * 260];
  int tid = threadIdx.x;
  int b = tid & 31, jg = tid >> 5;
  int j = blockIdx.x * 8 + jg;
  const int* src = (const int*)(ws + OFF_SRC);
  float acc0 = 0.f, acc1 = 0.f, acc2 = 0.f, acc3 = 0.f;
  for (int c = 0; c < 7; ++c) {
    __syncthreads();
#pragma unroll
    for (int q = 0; q < 32; ++q) {
      int i2 = q * 256 + tid;
      int bb = i2 >> 8, kk = i2 & 255;
      float v;
      if (c < 2)       v = emb[(long)src[t * 32 + bb] * 512 + c * 256 + kk];
      else if (c == 2) v = ws[OFF_RV + (long)t * 8192 + bb * 256 + kk];
      else             v = ws[OFF_H + (long)t * 32768 + bb * 1024 + (c - 3) * 256 + kk];
      xl[bb * 260 + kk] = v;
    }
    __syncthreads();
    const float* xp = &xl[b * 260];
    const float *w0, *w1, *w2, *w3;
    if (c < 3) {
      w0 = W_ih + (long)j * 768 + c * 256;
      w1 = W_ih + (long)(1024 + j) * 768 + c * 256;
      w2 = W_ih + (long)(2048 + j) * 768 + c * 256;
      w3 = W_ih + (long)(3072 + j) * 768 + c * 256;
    } else {
      w0 = W_hh + (long)j * 1024 + (c - 3) * 256;
      w1 = W_hh + (long)(1024 + j) * 1024 + (c - 3) * 256;
      w2 = W_hh + (long)(2048 + j) * 1024 + (c - 3) * 256;
      w3 = W_hh + (long)(3072 + j) * 1024 + (c - 3) * 256;
    }
#pragma unroll 4
    for (int k = 0; k < 256; k += 4) {
      float4 xv = *(const float4*)(xp + k);
      float4 a = *(const float4*)(w0 + k);
      float4 bb4 = *(const float4*)(w1 + k);
      float4 cc4 = *(const float4*)(w2 + k);
      float4 dd4 = *(const float4*)(w3 + k);
      acc0 += xv.x * a.x + xv.y * a.y + xv.z * a.z + xv.w * a.w;
      acc1 += xv.x * bb4.x + xv.y * bb4.y + xv.z * bb4.z + xv.w * bb4.w;
      acc2 += xv.x * cc4.x + xv.y * cc4.y + xv.z * cc4.z + xv.w * cc4.w;
      acc3 += xv.x * dd4.x + xv.y * dd4.y + xv.z * dd4.z + xv.w * dd4.w;
    }
  }
  float gi = acc0 + b_ih[j]        + b_hh[j];
  float gf = acc1 + b_ih[1024 + j] + b_hh[1024 + j];
  float gg = acc2 + b_ih[2048 + j] + b_hh[2048 + j];
  float go = acc3 + b_ih[3072 + j] + b_hh[3072 + j];
  long si = (long)b * 1024 + j;
  float sv = sigm(gf) * ws[OFF_S + si] + sigm(gi) * tanhf(gg);
  ws[OFF_S + si] = sv;
  ws[OFF_H + (long)(t + 1) * 32768 + si] = sigm(go) * tanhf(sv);
}

// ===== proj tiled: block = 16 outputs x 8 batches; h in LDS; w in regs =====
// grid dim3(30,4), 256 thr (4 waves). Weight row loaded once, reused 8x.
__global__ __launch_bounds__(256) void proj_kernel(
    int t, float* __restrict__ ws,
    const float* rk_w, const float* rk_b, const float* rs_w, const float* rs_b,
    const float* fg_w, const float* fg_b, const float* rm_w, const float* rm_b,
    const float* wk_w, const float* wk_b, const float* ws_w, const float* ws_b,
    const float* ev_w, const float* ev_b, const float* wv_w, const float* wv_b,
    const float* ag_w, const float* ag_b, const float* wg_w, const float* wg_b) {
  __shared__ float h_s[8][1032];
  int obase = blockIdx.x * 16;
  int bbase = blockIdx.y * 8;
  int tid = threadIdx.x;
  for (int q = 0; q < 32; ++q) {
    int idx = q * 256 + tid;          // 0..8191
    int bb = idx >> 10, kk = idx & 1023;
    h_s[bb][kk] = ws[OFF_H + (long)(t + 1) * 32768 + (long)(bbase + bb) * 1024 + kk];
  }
  __syncthreads();
  int wv = tid >> 6, lane = tid & 63;
  for (int oi = wv; oi < 16; oi += 4) {
    int o = obase + oi;
    if (o >= 471) continue;   // wave-uniform
    const float* w;
    float bias;
    if (o < 256)      { int wi = o >> 2, hh = o & 3; w = rk_w + (long)(hh * 64 + wi) * 1024; bias = rk_b[hh * 64 + wi]; }
    else if (o < 260) { int q = o - 256; w = rs_w + (long)q * 1024; bias = rs_b[q]; }
    else if (o < 264) { int q = o - 260; w = fg_w + (long)q * 1024; bias = fg_b[q]; }
    else if (o < 276) { int q = o - 264, m = q >> 2, hh = q & 3; w = rm_w + (long)(hh * 3 + m) * 1024; bias = rm_b[hh * 3 + m]; }
    else if (o < 340) { int q = o - 276; w = wk_w + (long)q * 1024; bias = wk_b[q]; }
    else if (o == 340){ w = ws_w; bias = ws_b[0]; }
    else if (o < 405) { int q = o - 341; w = ev_w + (long)q * 1024; bias = ev_b[q]; }
    else if (o < 469) { int q = o - 405; w = wv_w + (long)q * 1024; bias = wv_b[q]; }
    else if (o == 469){ w = ag_w; bias = ag_b[0]; }
    else              { w = wg_w; bias = wg_b[0]; }
    float wreg[16];
#pragma unroll
    for (int i = 0; i < 16; ++i) wreg[i] = w[lane + 64 * i];
#pragma unroll
    for (int bb = 0; bb < 8; ++bb) {
      float s = 0.f;
#pragma unroll
      for (int i = 0; i < 16; ++i) s += h_s[bb][lane + 64 * i] * wreg[i];
#pragma unroll
      for (int off = 32; off; off >>= 1) s += __shfl_xor(s, off);
      if (lane == 0) ws[OFF_PROJ + (long)(bbase + bb) * 512 + o] = s + bias;
    }
  }
}

// ===== block reductions over 128 threads =====
__device__ __forceinline__ float blk_max(float v, float* red, int n) {
  red[n] = v; __syncthreads();
#pragma unroll
  for (int s = 64; s > 0; s >>= 1) { if (n < s) red[n] = fmaxf(red[n], red[n + s]); __syncthreads(); }
  float r = red[0]; __syncthreads();
  return r;
}
__device__ __forceinline__ float blk_sum(float v, float* red, int n) {
  red[n] = v; __syncthreads();
#pragma unroll
  for (int s = 64; s > 0; s >>= 1) { if (n < s) red[n] += red[n + s]; __syncthreads(); }
  float r = red[0]; __syncthreads();
  return r;
}

// ===== memA (r7 exact): usage, sort, alloc, write attn, ww, p, mem, links ==
__global__ __launch_bounds__(128) void memA_kernel(float* __restrict__ ws) {
  __shared__ float su[128], lg[128], red[128], wwl[128], pl[128];
  __shared__ float kwl[64], knl[64], dl[64];
  int b = blockIdx.x, n = threadIdx.x;
  const float* pj = ws + OFF_PROJ + b * 512;
  float* u   = ws + OFF_U  + b * 128;
  float* wwp = ws + OFF_WW + b * 128;
  float* pp  = ws + OFF_P  + b * 128;
  const float* rwp = ws + OFF_RW + b * 512;
  float* memp = ws + OFF_MEM + (long)b * 8192;
  float* lk   = ws + OFF_LINKS + (long)b * 16384;

  float fg0 = sigm(pj[260]), fg1 = sigm(pj[261]), fg2 = sigm(pj[262]), fg3 = sigm(pj[263]);
  float r0 = rwp[n * 4], r1 = rwp[n * 4 + 1], r2 = rwp[n * 4 + 2], r3 = rwp[n * 4 + 3];
  float psi = expf(logf(1.f - fg0 * r0) + logf(1.f - fg1 * r1) +
                   logf(1.f - fg2 * r2) + logf(1.f - fg3 * r3));
  float uu = u[n], wwo = wwp[n];
  uu = (uu + wwo - uu * wwo) * psi;
  u[n] = uu;
  su[n] = uu;
  if (n < 64) {
    kwl[n] = pj[276 + n];
    dl[n] = sigm(pj[405 + n]) - sigm(pj[341 + n]);  // writev - erase
  }
  __syncthreads();
  float kn2 = 0.f;
#pragma unroll
  for (int w = 0; w < 64; ++w) kn2 += kwl[w] * kwl[w];
  float kn = sqrtf(kn2);
  if (n < 64) knl[n] = kwl[n] / kn;
  // bitonic ascending sort
  for (int k = 2; k <= 128; k <<= 1) {
    for (int jj = k >> 1; jj > 0; jj >>= 1) {
      int ixj = n ^ jj;
      if (ixj > n) {
        float a1 = su[n], a2 = su[ixj];
        if (((n & k) == 0) ? (a1 > a2) : (a1 < a2)) { su[n] = a2; su[ixj] = a1; }
      }
      __syncthreads();
    }
  }
  // Hillis-Steele inclusive scan of logs
  lg[n] = logf(su[n]);
  __syncthreads();
  for (int off = 1; off < 128; off <<= 1) {
    float v = (n >= off) ? lg[n - off] : 0.f;
    __syncthreads();
    lg[n] += v;
    __syncthreads();
  }
  float a_n = (1.f - su[n]) * expf(lg[n] - logf(su[n]));
  float mrow[64];
  float sq = 0.f;
#pragma unroll
  for (int w = 0; w < 64; ++w) { float m = memp[n * 64 + w]; mrow[w] = m; sq += m * m; }
  float den = sqrtf(sq) + EPSF;
#pragma unroll
  for (int w = 0; w < 64; ++w) mrow[w] = mrow[w] / den;
  float dot = 0.f;
#pragma unroll
  for (int w = 0; w < 64; ++w) dot += mrow[w] * knl[w];
  float score = dot * oneplus_(pj[340]);
  float mx = blk_max(score, red, n);
  float e = expf(score - mx);
  float cw = e / blk_sum(e, red, n);
  float ag = sigm(pj[469]), wg = sigm(pj[470]);
  float wwn = wg * (ag * a_n + (1.f - ag) * cw);
  wwp[n] = wwn; wwl[n] = wwn;
  float sumww = blk_sum(wwn, red, n);
  float pn = (1.f - sumww) * pp[n] + wwn;
  pp[n] = pn; pl[n] = pn;
  __syncthreads();
#pragma unroll
  for (int w = 0; w < 64; ++w) memp[n * 64 + w] = mrow[w] + wwn * dl[w];
  for (int k2 = 0; k2 < 128; ++k2) {
    long idx = (long)k2 * 128 + n;
    float v = lk[idx] * (1.f - (wwl[k2] + wwl[n])) + wwl[k2] * pl[n];
    lk[idx] = (k2 == n) ? 0.f : v;
  }
}

// ===== memBC (r7 exact): renorm mem, read attn, f/b, new rw, rv ============
__global__ __launch_bounds__(128) void memBC_kernel(int t, float* __restrict__ ws) {
  __shared__ float red[128], rwold[512], rwnew[512], kl[256];
  __shared__ float mem_s[128 * 64];
  int b = blockIdx.x, n = threadIdx.x;
  const float* pj = ws + OFF_PROJ + b * 512;
  float* rwp = ws + OFF_RW + b * 512;
  float* memp = ws + OFF_MEM + (long)b * 8192;
  const float* lk = ws + OFF_LINKS + (long)b * 16384;
#pragma unroll
  for (int h = 0; h < 4; ++h) rwold[n * 4 + h] = rwp[n * 4 + h];
  if (n < 64) {
#pragma unroll
    for (int h = 0; h < 4; ++h) kl[n * 4 + h] = pj[n * 4 + h];
  }
  __syncthreads();
  float mrow[64];
  float sq = 0.f;
#pragma unroll
  for (int w = 0; w < 64; ++w) { float m = memp[n * 64 + w]; mrow[w] = m; sq += m * m; }
  float den2 = sqrtf(sq) + EPSF;
#pragma unroll
  for (int w = 0; w < 64; ++w) {
    mrow[w] = mrow[w] / den2;
    memp[n * 64 + w] = mrow[w];
    mem_s[n * 64 + w] = mrow[w];
  }
  float cr_[4];
#pragma unroll
  for (int h = 0; h < 4; ++h) {
    float s3 = 0.f;
#pragma unroll
    for (int w = 0; w < 64; ++w) { float kv = kl[w * 4 + h]; s3 += kv * kv; }
    float knh = sqrtf(s3);
    float d2 = 0.f;
#pragma unroll
    for (int w = 0; w < 64; ++w) d2 += mrow[w] * (kl[w * 4 + h] / knh);
    float sc = d2 * oneplus_(pj[256 + h]);
    float mxh = blk_max(sc, red, n);
    float eh = expf(sc - mxh);
    cr_[h] = eh / blk_sum(eh, red, n);
  }
  float f0 = 0, f1 = 0, f2 = 0, f3 = 0, b0 = 0, b1 = 0, b2 = 0, b3 = 0;
  for (int jj = 0; jj < 128; ++jj) {
    float lrow = lk[(long)n * 128 + jj];
    float lcol = lk[(long)jj * 128 + n];
    float q0 = rwold[jj * 4], q1 = rwold[jj * 4 + 1], q2 = rwold[jj * 4 + 2], q3 = rwold[jj * 4 + 3];
    f0 += lrow * q0; f1 += lrow * q1; f2 += lrow * q2; f3 += lrow * q3;
    b0 += lcol * q0; b1 += lcol * q1; b2 += lcol * q2; b3 += lcol * q3;
  }
  float fv[4] = {f0, f1, f2, f3}, bv[4] = {b0, b1, b2, b3};
#pragma unroll
  for (int h = 0; h < 4; ++h) {
    float m0 = pj[264 + h], m1 = pj[264 + 4 + h], m2 = pj[264 + 8 + h];
    float mm = fmaxf(m0, fmaxf(m1, m2));
    float e0 = expf(m0 - mm), e1 = expf(m1 - mm), e2 = expf(m2 - mm);
    float inv = 1.f / (e0 + e1 + e2);
    float rwv = (e0 * inv) * bv[h] + (e1 * inv) * cr_[h] + (e2 * inv) * fv[h];
    rwp[n * 4 + h] = rwv;
    rwnew[n * 4 + h] = rwv;
  }
  __syncthreads();
  int w2 = n & 63, which = n >> 6;
  float rv0 = 0.f, rv1 = 0.f;
  for (int jj = 0; jj < 128; ++jj) {
    float mv = mem_s[jj * 64 + w2];
    rv0 += mv * rwnew[jj * 4 + which * 2];
    rv1 += mv * rwnew[jj * 4 + which * 2 + 1];
  }
  float* RVp = ws + OFF_RV + (long)(t + 1) * 8192 + b * 256;
  RVp[w2 * 4 + which * 2]     = rv0;
  RVp[w2 * 4 + which * 2 + 1] = rv1;
}

// ===== out_gemm: [2048,16000], K=1280, fp32; bank-conflict-free micro-tile ==
// Thread covers rows ty*8..+7, cols {tx*4..+3, 64+tx*4..+3} (16B-stride reads)
__global__ __launch_bounds__(256) void out_gemm(
    const float* __restrict__ ws, const float* __restrict__ Why_w,
    const float* __restrict__ Why_b, const float* __restrict__ Wry_w,
    float* __restrict__ out) {
  __shared__ float al[16 * 132];
  __shared__ float bl[16 * 132];
  const float* Hp  = ws + OFF_H + 32768;   // [2048][1024]
  const float* RVp = ws + OFF_RV + 8192;   // [2048][256]
  int tid = threadIdx.x;
  int tx = tid & 15, ty = tid >> 4;
  int col0 = blockIdx.x * 128, row0 = blockIdx.y * 128;
  float acc[8][8];
#pragma unroll
  for (int i = 0; i < 8; ++i)
#pragma unroll
    for (int j = 0; j < 8; ++j) acc[i][j] = 0.f;
  for (int kt = 0; kt < 80; ++kt) {
    int k0 = kt * 16;
    __syncthreads();
#pragma unroll
    for (int q = 0; q < 8; ++q) {
      int i2 = q * 256 + tid;
      int r = i2 >> 4, k = i2 & 15;
      int gk = k0 + k;
      float va = (gk < 1024) ? Hp[(long)(row0 + r) * 1024 + gk]
                             : RVp[(long)(row0 + r) * 256 + gk - 1024];
      al[k * 132 + r] = va;
      float vb = (gk < 1024) ? Why_w[(long)(col0 + r) * 1024 + gk]
                             : Wry_w[(long)(col0 + r) * 256 + gk - 1024];
      bl[k * 132 + r] = vb;
    }
    __syncthreads();
#pragma unroll
    for (int k = 0; k < 16; ++k) {
      float4 a0 = *(const float4*)&al[k * 132 + ty * 8];
      float4 a1 = *(const float4*)&al[k * 132 + ty * 8 + 4];
      float4 c0 = *(const float4*)&bl[k * 132 + tx * 4];
      float4 c1 = *(const float4*)&bl[k * 132 + 64 + tx * 4];
      float ar[8] = {a0.x, a0.y, a0.z, a0.w, a1.x, a1.y, a1.z, a1.w};
      float br[8] = {c0.x, c0.y, c0.z, c0.w, c1.x, c1.y, c1.z, c1.w};
#pragma unroll
      for (int i = 0; i < 8; ++i)
#pragma unroll
        for (int j = 0; j < 8; ++j) acc[i][j] += ar[i] * br[j];
    }
  }
  float4 bb0 = *(const float4*)&Why_b[col0 + tx * 4];
  float4 bb1 = *(const float4*)&Why_b[col0 + 64 + tx * 4];
  float bias[8] = {bb0.x, bb0.y, bb0.z, bb0.w, bb1.x, bb1.y, bb1.z, bb1.w};
#pragma unroll
  for (int i = 0; i < 8; ++i) {
    long r = row0 + ty * 8 + i;
    float* op0 = out + r * 16000 + col0 + tx * 4;
    float* op1 = out + r * 16000 + col0 + 64 + tx * 4;
    float4 o0 = {acc[i][0] + bias[0], acc[i][1] + bias[1], acc[i][2] + bias[2], acc[i][3] + bias[3]};
    float4 o1 = {acc[i][4] + bias[4], acc[i][5] + bias[5], acc[i][6] + bias[6], acc[i][7] + bias[7]};
    *(float4*)op0 = o0;
    *(float4*)op1 = o1;
  }
}

extern "C" void kernel_launch(void* const* d_in, const int* in_sizes, int n_in,
                              void* d_out, int out_size, void* d_ws, size_t ws_size,
                              hipStream_t stream) {
  const void* src_raw = d_in[0];
  const float* emb   = (const float*)d_in[1];
  const float* W_ih  = (const float*)d_in[2];
  const float* W_hh  = (const float*)d_in[3];
  const float* b_ih  = (const float*)d_in[4];
  const float* b_hh  = (const float*)d_in[5];
  const float* rk_w  = (const float*)d_in[6];
  const float* rk_b  = (const float*)d_in[7];
  const float* rs_w  = (const float*)d_in[8];
  const float* rs_b  = (const float*)d_in[9];
  const float* fg_w  = (const float*)d_in[10];
  const float* fg_b  = (const float*)d_in[11];
  const float* rm_w  = (const float*)d_in[12];
  const float* rm_b  = (const float*)d_in[13];
  const float* wk_w  = (const float*)d_in[14];
  const float* wk_b  = (const float*)d_in[15];
  const float* ws_w  = (const float*)d_in[16];
  const float* ws_b  = (const float*)d_in[17];
  const float* ev_w  = (const float*)d_in[18];
  const float* ev_b  = (const float*)d_in[19];
  const float* wv_w  = (const float*)d_in[20];
  const float* wv_b  = (const float*)d_in[21];
  const float* ag_w  = (const float*)d_in[22];
  const float* ag_b  = (const float*)d_in[23];
  const float* wg_w  = (const float*)d_in[24];
  const float* wg_b  = (const float*)d_in[25];
  const float* Why_w = (const float*)d_in[26];
  const float* Why_b = (const float*)d_in[27];
  const float* Wry_w = (const float*)d_in[28];
  float* ws = (float*)d_ws;
  float* out = (float*)d_out;

  src_decode<<<1, 256, 0, stream>>>(src_raw, ws);
  init_kernel<<<512, 256, 0, stream>>>(ws);
  for (int t = 0; t < TN; ++t) {
    gates4_kernel<<<128, 256, 0, stream>>>(t, emb, W_ih, W_hh, b_ih, b_hh, ws);
    proj_kernel<<<dim3(30, 4), 256, 0, stream>>>(t, ws, rk_w, rk_b, rs_w, rs_b, fg_w, fg_b,
                                                 rm_w, rm_b, wk_w, wk_b, ws_w, ws_b,
                                                 ev_w, ev_b, wv_w, wv_b, ag_w, ag_b, wg_w, wg_b);
    memA_kernel<<<32, 128, 0, stream>>>(ws);
    memBC_kernel<<<32, 128, 0, stream>>>(t, ws);
  }
  out_gemm<<<dim3(125, 16), 256, 0, stream>>>(ws, Why_w, Why_b, Wry_w, out);
}

// Round 12
// 13963.463 us; speedup vs baseline: 1.7701x; 1.0328x over previous
//
#include <hip/hip_runtime.h>
#include <math.h>

// ---- problem dims ----
#define TN 64
#define BN 32
#define EPSF 1e-6f

// ---- workspace layout (floats): full H/RV history for deferred out-GEMM ----
constexpr long OFF_H     = 0;                       // 65 * 32*1024
constexpr long OFF_RV    = OFF_H    + 65L*32768;    // 65 * 32*256
constexpr long OFF_S     = OFF_RV   + 65L*8192;     // 32768
constexpr long OFF_RW    = OFF_S    + 32768;        // B*N*HD = 16384
constexpr long OFF_WW    = OFF_RW   + 16384;        // B*N
constexpr long OFF_U     = OFF_WW   + 4096;
constexpr long OFF_P     = OFF_U    + 4096;
constexpr long OFF_MEM   = OFF_P    + 4096;         // B*N*WD = 262144
constexpr long OFF_LINKS = OFF_MEM  + 262144;       // B*N*N = 524288
constexpr long OFF_PROJ  = OFF_LINKS+ 524288;       // B*512 (471 used)
constexpr long OFF_SRC   = OFF_PROJ + 16384;        // 2048 ints
// total ≈ 14.1 MB (proven footprint)

__device__ __forceinline__ float sigm(float x) { return 1.f / (1.f + expf(-x)); }
__device__ __forceinline__ float oneplus_(float x) {
  return 1.f + fmaxf(x, 0.f) + log1pf(expf(-fabsf(x)));
}

// ===== src width auto-detect + decode to int32 (validated round 6) =========
__global__ void src_decode(const void* __restrict__ src_raw, float* __restrict__ ws) {
  __shared__ int is64_s;
  if (threadIdx.x == 0) is64_s = 1;
  __syncthreads();
  const long long* s64 = (const long long*)src_raw;
  for (int i = threadIdx.x; i < 1024; i += 256) {
    long long v = s64[i];
    if (v < 0 || v >= 32000) is64_s = 0;
  }
  __syncthreads();
  int* dst = (int*)(ws + OFF_SRC);
  if (is64_s) {
    for (int i = threadIdx.x; i < 2048; i += 256) dst[i] = (int)s64[i];
  } else {
    const int* s32 = (const int*)src_raw;
    for (int i = threadIdx.x; i < 2048; i += 256) dst[i] = s32[i];
  }
}

// ================= init: H slot0, RV slot0, state; U=EPS ====================
__global__ void init_kernel(float* ws) {
  long i0 = (long)blockIdx.x * blockDim.x + threadIdx.x;
  long stride = (long)gridDim.x * blockDim.x;
  for (long x = i0; x < 32768; x += stride) ws[OFF_H + x] = 0.f;
  for (long x = i0; x < 8192;  x += stride) ws[OFF_RV + x] = 0.f;
  const long zlen = OFF_PROJ - OFF_S;
  for (long x = i0; x < zlen; x += stride) {
    long g = OFF_S + x;
    ws[g] = (g >= OFF_U && g < OFF_U + 4096) ? EPSF : 0.f;
  }
}

// ===== gates4: fused gates-GEMM + LSTM pointwise (r7 exact: 128 blk x 256) =
__global__ __launch_bounds__(256) void gates4_kernel(
    int t, const float* __restrict__ emb,
    const float* __restrict__ W_ih, const float* __restrict__ W_hh,
    const float* __restrict__ b_ih, const float* __restrict__ b_hh,
    float* __restrict__ ws) {
  __shared__ float xl[32 * 260];
  int tid = threadIdx.x;
  int b = tid & 31, jg = tid >> 5;
  int j = blockIdx.x * 8 + jg;
  const int* src = (const int*)(ws + OFF_SRC);
  float acc0 = 0.f, acc1 = 0.f, acc2 = 0.f, acc3 = 0.f;
  for (int c = 0; c < 7; ++c) {
    __syncthreads();
#pragma unroll
    for (int q = 0; q < 32; ++q) {
      int i2 = q * 256 + tid;
      int bb = i2 >> 8, kk = i2 & 255;
      float v;
      if (c < 2)       v = emb[(long)src[t * 32 + bb] * 512 + c * 256 + kk];
      else if (c == 2) v = ws[OFF_RV + (long)t * 8192 + bb * 256 + kk];
      else             v = ws[OFF_H + (long)t * 32768 + bb * 1024 + (c - 3) * 256 + kk];
      xl[bb * 260 + kk] = v;
    }
    __syncthreads();
    const float* xp = &xl[b * 260];
    const float *w0, *w1, *w2, *w3;
    if (c < 3) {
      w0 = W_ih + (long)j * 768 + c * 256;
      w1 = W_ih + (long)(1024 + j) * 768 + c * 256;
      w2 = W_ih + (long)(2048 + j) * 768 + c * 256;
      w3 = W_ih + (long)(3072 + j) * 768 + c * 256;
    } else {
      w0 = W_hh + (long)j * 1024 + (c - 3) * 256;
      w1 = W_hh + (long)(1024 + j) * 1024 + (c - 3) * 256;
      w2 = W_hh + (long)(2048 + j) * 1024 + (c - 3) * 256;
      w3 = W_hh + (long)(3072 + j) * 1024 + (c - 3) * 256;
    }
#pragma unroll 4
    for (int k = 0; k < 256; k += 4) {
      float4 xv = *(const float4*)(xp + k);
      float4 a = *(const float4*)(w0 + k);
      float4 bb4 = *(const float4*)(w1 + k);
      float4 cc4 = *(const float4*)(w2 + k);
      float4 dd4 = *(const float4*)(w3 + k);
      acc0 += xv.x * a.x + xv.y * a.y + xv.z * a.z + xv.w * a.w;
      acc1 += xv.x * bb4.x + xv.y * bb4.y + xv.z * bb4.z + xv.w * bb4.w;
      acc2 += xv.x * cc4.x + xv.y * cc4.y + xv.z * cc4.z + xv.w * cc4.w;
      acc3 += xv.x * dd4.x + xv.y * dd4.y + xv.z * dd4.z + xv.w * dd4.w;
    }
  }
  float gi = acc0 + b_ih[j]        + b_hh[j];
  float gf = acc1 + b_ih[1024 + j] + b_hh[1024 + j];
  float gg = acc2 + b_ih[2048 + j] + b_hh[2048 + j];
  float go = acc3 + b_ih[3072 + j] + b_hh[3072 + j];
  long si = (long)b * 1024 + j;
  float sv = sigm(gf) * ws[OFF_S + si] + sigm(gi) * tanhf(gg);
  ws[OFF_S + si] = sv;
  ws[OFF_H + (long)(t + 1) * 32768 + si] = sigm(go) * tanhf(sv);
}

// ===== proj tiled (r11 exact): 16 outputs x 8 batches per block ============
__global__ __launch_bounds__(256) void proj_kernel(
    int t, float* __restrict__ ws,
    const float* rk_w, const float* rk_b, const float* rs_w, const float* rs_b,
    const float* fg_w, const float* fg_b, const float* rm_w, const float* rm_b,
    const float* wk_w, const float* wk_b, const float* ws_w, const float* ws_b,
    const float* ev_w, const float* ev_b, const float* wv_w, const float* wv_b,
    const float* ag_w, const float* ag_b, const float* wg_w, const float* wg_b) {
  __shared__ float h_s[8][1032];
  int obase = blockIdx.x * 16;
  int bbase = blockIdx.y * 8;
  int tid = threadIdx.x;
  for (int q = 0; q < 32; ++q) {
    int idx = q * 256 + tid;          // 0..8191
    int bb = idx >> 10, kk = idx & 1023;
    h_s[bb][kk] = ws[OFF_H + (long)(t + 1) * 32768 + (long)(bbase + bb) * 1024 + kk];
  }
  __syncthreads();
  int wv = tid >> 6, lane = tid & 63;
  for (int oi = wv; oi < 16; oi += 4) {
    int o = obase + oi;
    if (o >= 471) continue;   // wave-uniform
    const float* w;
    float bias;
    if (o < 256)      { int wi = o >> 2, hh = o & 3; w = rk_w + (long)(hh * 64 + wi) * 1024; bias = rk_b[hh * 64 + wi]; }
    else if (o < 260) { int q = o - 256; w = rs_w + (long)q * 1024; bias = rs_b[q]; }
    else if (o < 264) { int q = o - 260; w = fg_w + (long)q * 1024; bias = fg_b[q]; }
    else if (o < 276) { int q = o - 264, m = q >> 2, hh = q & 3; w = rm_w + (long)(hh * 3 + m) * 1024; bias = rm_b[hh * 3 + m]; }
    else if (o < 340) { int q = o - 276; w = wk_w + (long)q * 1024; bias = wk_b[q]; }
    else if (o == 340){ w = ws_w; bias = ws_b[0]; }
    else if (o < 405) { int q = o - 341; w = ev_w + (long)q * 1024; bias = ev_b[q]; }
    else if (o < 469) { int q = o - 405; w = wv_w + (long)q * 1024; bias = wv_b[q]; }
    else if (o == 469){ w = ag_w; bias = ag_b[0]; }
    else              { w = wg_w; bias = wg_b[0]; }
    float wreg[16];
#pragma unroll
    for (int i = 0; i < 16; ++i) wreg[i] = w[lane + 64 * i];
#pragma unroll
    for (int bb = 0; bb < 8; ++bb) {
      float s = 0.f;
#pragma unroll
      for (int i = 0; i < 16; ++i) s += h_s[bb][lane + 64 * i] * wreg[i];
#pragma unroll
      for (int off = 32; off; off >>= 1) s += __shfl_xor(s, off);
      if (lane == 0) ws[OFF_PROJ + (long)(bbase + bb) * 512 + o] = s + bias;
    }
  }
}

// ===== reductions over 256 threads (neutral elems keep 128-tree bitwise) ===
__device__ __forceinline__ float blk_max256(float v, float* red, int tid) {
  red[tid] = v; __syncthreads();
#pragma unroll
  for (int s = 128; s > 0; s >>= 1) { if (tid < s) red[tid] = fmaxf(red[tid], red[tid + s]); __syncthreads(); }
  float r = red[0]; __syncthreads();
  return r;
}
__device__ __forceinline__ float blk_sum256(float v, float* red, int tid) {
  red[tid] = v; __syncthreads();
#pragma unroll
  for (int s = 128; s > 0; s >>= 1) { if (tid < s) red[tid] += red[tid + s]; __syncthreads(); }
  float r = red[0]; __syncthreads();
  return r;
}

// ===== memAB: memA+memBC fused; mem AND links in LDS; 32 blk x 256 thr =====
constexpr int SMEMF = 8320 + 16512 + 256 + 4*128 + 3*64 + 256 + 512 + 512 + 1024 + 1024;
__global__ __launch_bounds__(256) void memAB_kernel(int t, float* __restrict__ ws) {
  extern __shared__ float sm[];
  float* mem_s = sm;               // [128][65]
  float* lk_s  = sm + 8320;        // [128][129]
  float* red   = sm + 24832;       // 256
  float* su    = sm + 25088;       // 128
  float* lg    = sm + 25216;       // 128
  float* wwl   = sm + 25344;       // 128
  float* pl    = sm + 25472;       // 128
  float* kwl   = sm + 25600;       // 64
  float* knl   = sm + 25664;       // 64
  float* dl    = sm + 25728;       // 64
  float* kl    = sm + 25792;       // 256
  float* rwold = sm + 26048;       // 512
  float* rwnew = sm + 26560;       // 512
  float* fpart = sm + 27072;       // 1024 (2 halves x 128 x 4)
  float* bpart = sm + 28096;       // 1024
  int b = blockIdx.x, tid = threadIdx.x;
  int n = tid & 127, half = tid >> 7;
  const float* pj = ws + OFF_PROJ + b * 512;
  float* u    = ws + OFF_U  + b * 128;
  float* wwp  = ws + OFF_WW + b * 128;
  float* pp   = ws + OFF_P  + b * 128;
  float* rwp  = ws + OFF_RW + b * 512;
  float* memp = ws + OFF_MEM + (long)b * 8192;
  float* lk   = ws + OFF_LINKS + (long)b * 16384;

  for (int i = tid; i < 8192; i += 256) mem_s[(i >> 6) * 65 + (i & 63)] = memp[i];
  for (int i = tid; i < 16384; i += 256) lk_s[(i >> 7) * 129 + (i & 127)] = lk[i];

  // ---- phase A per-slot (half 0) ----
  if (half == 0) {
    float fg0 = sigm(pj[260]), fg1 = sigm(pj[261]), fg2 = sigm(pj[262]), fg3 = sigm(pj[263]);
    float r0 = rwp[n * 4], r1 = rwp[n * 4 + 1], r2 = rwp[n * 4 + 2], r3 = rwp[n * 4 + 3];
    rwold[n * 4] = r0; rwold[n * 4 + 1] = r1; rwold[n * 4 + 2] = r2; rwold[n * 4 + 3] = r3;
    float psi = expf(logf(1.f - fg0 * r0) + logf(1.f - fg1 * r1) +
                     logf(1.f - fg2 * r2) + logf(1.f - fg3 * r3));
    float uu = u[n], wwo = wwp[n];
    uu = (uu + wwo - uu * wwo) * psi;
    u[n] = uu;
    su[n] = uu;
  }
  if (tid < 64) {
    kwl[tid] = pj[276 + tid];
    dl[tid] = sigm(pj[405 + tid]) - sigm(pj[341 + tid]);  // writev - erase
  }
  if (tid >= 128 && tid < 192) {
    int q = tid - 128;
#pragma unroll
    for (int h = 0; h < 4; ++h) kl[q * 4 + h] = pj[q * 4 + h];
  }
  __syncthreads();
  float kn2 = 0.f;
#pragma unroll
  for (int w = 0; w < 64; ++w) kn2 += kwl[w] * kwl[w];
  float kn = sqrtf(kn2);
  if (tid < 64) knl[tid] = kwl[tid] / kn;
  // bitonic ascending sort (half0 acts; all sync)
  for (int k = 2; k <= 128; k <<= 1) {
    for (int jj = k >> 1; jj > 0; jj >>= 1) {
      if (half == 0) {
        int ixj = n ^ jj;
        if (ixj > n) {
          float a1 = su[n], a2 = su[ixj];
          if (((n & k) == 0) ? (a1 > a2) : (a1 < a2)) { su[n] = a2; su[ixj] = a1; }
        }
      }
      __syncthreads();
    }
  }
  // Hillis-Steele inclusive scan of logs
  if (half == 0) lg[n] = logf(su[n]);
  __syncthreads();
  for (int off = 1; off < 128; off <<= 1) {
    float v = (half == 0 && n >= off) ? lg[n - off] : 0.f;
    __syncthreads();
    if (half == 0) lg[n] += v;
    __syncthreads();
  }
  // write attention (half0 computes; reductions 256-wide w/ neutral elems)
  float mrow[64];
  float score = -3.4e38f, e = 0.f, wwn = 0.f;
  if (half == 0) {
    float a_n = (1.f - su[n]) * expf(lg[n] - logf(su[n]));
    float sq = 0.f;
#pragma unroll
    for (int w = 0; w < 64; ++w) { float m = mem_s[n * 65 + w]; mrow[w] = m; sq += m * m; }
    float den = sqrtf(sq) + EPSF;
#pragma unroll
    for (int w = 0; w < 64; ++w) mrow[w] = mrow[w] / den;
    float dot = 0.f;
#pragma unroll
    for (int w = 0; w < 64; ++w) dot += mrow[w] * knl[w];
    score = dot * oneplus_(pj[340]);
    // stash a_n in 'e' slot temporarily? no — recompute path below keeps vars
    e = a_n;   // reuse register: e holds a_n until exp step
  }
  float mx = blk_max256(score, red, tid);
  float a_n = e;      // (half0 only meaningful)
  e = (half == 0) ? expf(score - mx) : 0.f;
  float esum = blk_sum256(e, red, tid);
  if (half == 0) {
    float cw = e / esum;
    float ag = sigm(pj[469]), wg = sigm(pj[470]);
    wwn = wg * (ag * a_n + (1.f - ag) * cw);
    wwp[n] = wwn; wwl[n] = wwn;
  }
  float sumww = blk_sum256((half == 0) ? wwn : 0.f, red, tid);
  if (half == 0) {
    float pn = (1.f - sumww) * pp[n] + wwn;
    pp[n] = pn; pl[n] = pn;
  }
  __syncthreads();   // wwl, pl visible
  if (half == 0) {
#pragma unroll
    for (int w = 0; w < 64; ++w) mem_s[n * 65 + w] = mrow[w] + wwn * dl[w];
  }
  // link update: thread (col=n, rows half*64..half*64+63)
  {
    float wn = wwl[n], pcol = pl[n];
    int base = half * 64;
    for (int q = 0; q < 64; ++q) {
      int k2 = base + q;
      float v = lk_s[k2 * 129 + n] * (1.f - (wwl[k2] + wn)) + wwl[k2] * pcol;
      lk_s[k2 * 129 + n] = (k2 == n) ? 0.f : v;
    }
  }
  __syncthreads();

  // ---- phase B ----
  if (half == 0) {
    float sq = 0.f;
#pragma unroll
    for (int w = 0; w < 64; ++w) { float m = mem_s[n * 65 + w]; mrow[w] = m; sq += m * m; }
    float den2 = sqrtf(sq) + EPSF;
#pragma unroll
    for (int w = 0; w < 64; ++w) { mrow[w] = mrow[w] / den2; mem_s[n * 65 + w] = mrow[w]; }
  }
  __syncthreads();   // final mem visible to all (for rv)
  float cr_[4];
#pragma unroll
  for (int h = 0; h < 4; ++h) {
    float s3 = 0.f;
#pragma unroll
    for (int w = 0; w < 64; ++w) { float kv = kl[w * 4 + h]; s3 += kv * kv; }
    float knh = sqrtf(s3);
    float sc = -3.4e38f;
    if (half == 0) {
      float d2 = 0.f;
#pragma unroll
      for (int w = 0; w < 64; ++w) d2 += mrow[w] * (kl[w * 4 + h] / knh);
      sc = d2 * oneplus_(pj[256 + h]);
    }
    float mxh = blk_max256(sc, red, tid);
    float eh = (half == 0) ? expf(sc - mxh) : 0.f;
    float ehs = blk_sum256(eh, red, tid);
    cr_[h] = eh / ehs;
  }
  // f/b partials over half the rows each (LDS, conflict-free stride 129)
  {
    float f0 = 0, f1 = 0, f2 = 0, f3 = 0, b0 = 0, b1 = 0, b2 = 0, b3 = 0;
    int base = half * 64;
    for (int q = 0; q < 64; ++q) {
      int jj = base + q;
      float lrow = lk_s[n * 129 + jj];
      float lcol = lk_s[jj * 129 + n];
      float q0 = rwold[jj * 4], q1 = rwold[jj * 4 + 1], q2 = rwold[jj * 4 + 2], q3 = rwold[jj * 4 + 3];
      f0 += lrow * q0; f1 += lrow * q1; f2 += lrow * q2; f3 += lrow * q3;
      b0 += lcol * q0; b1 += lcol * q1; b2 += lcol * q2; b3 += lcol * q3;
    }
    int o = half * 512 + n * 4;
    fpart[o] = f0; fpart[o + 1] = f1; fpart[o + 2] = f2; fpart[o + 3] = f3;
    bpart[o] = b0; bpart[o + 1] = b1; bpart[o + 2] = b2; bpart[o + 3] = b3;
  }
  __syncthreads();
  if (half == 0) {
#pragma unroll
    for (int h = 0; h < 4; ++h) {
      float fv = fpart[n * 4 + h] + fpart[512 + n * 4 + h];
      float bv = bpart[n * 4 + h] + bpart[512 + n * 4 + h];
      float m0 = pj[264 + h], m1 = pj[264 + 4 + h], m2 = pj[264 + 8 + h];
      float mm = fmaxf(m0, fmaxf(m1, m2));
      float e0 = expf(m0 - mm), e1 = expf(m1 - mm), e2 = expf(m2 - mm);
      float inv = 1.f / (e0 + e1 + e2);
      float rwv = (e0 * inv) * bv + (e1 * inv) * cr_[h] + (e2 * inv) * fv;
      rwp[n * 4 + h] = rwv;
      rwnew[n * 4 + h] = rwv;
    }
  }
  __syncthreads();
  // stores (coalesced)
  for (int i = tid; i < 8192; i += 256) memp[i] = mem_s[(i >> 6) * 65 + (i & 63)];
  for (int i = tid; i < 16384; i += 256) lk[i] = lk_s[(i >> 7) * 129 + (i & 127)];
  // rv: 256 threads, one output each
  {
    int w2 = tid & 63, which = tid >> 6;
    float rv = 0.f;
    for (int jj = 0; jj < 128; ++jj) rv += mem_s[jj * 65 + w2] * rwnew[jj * 4 + which];
    ws[OFF_RV + (long)(t + 1) * 8192 + b * 256 + w2 * 4 + which] = rv;
  }
}

// ===== out_gemm (r11 exact): conflict-free micro-tile ======================
__global__ __launch_bounds__(256) void out_gemm(
    const float* __restrict__ ws, const float* __restrict__ Why_w,
    const float* __restrict__ Why_b, const float* __restrict__ Wry_w,
    float* __restrict__ out) {
  __shared__ float al[16 * 132];
  __shared__ float bl[16 * 132];
  const float* Hp  = ws + OFF_H + 32768;   // [2048][1024]
  const float* RVp = ws + OFF_RV + 8192;   // [2048][256]
  int tid = threadIdx.x;
  int tx = tid & 15, ty = tid >> 4;
  int col0 = blockIdx.x * 128, row0 = blockIdx.y * 128;
  float acc[8][8];
#pragma unroll
  for (int i = 0; i < 8; ++i)
#pragma unroll
    for (int j = 0; j < 8; ++j) acc[i][j] = 0.f;
  for (int kt = 0; kt < 80; ++kt) {
    int k0 = kt * 16;
    __syncthreads();
#pragma unroll
    for (int q = 0; q < 8; ++q) {
      int i2 = q * 256 + tid;
      int r = i2 >> 4, k = i2 & 15;
      int gk = k0 + k;
      float va = (gk < 1024) ? Hp[(long)(row0 + r) * 1024 + gk]
                             : RVp[(long)(row0 + r) * 256 + gk - 1024];
      al[k * 132 + r] = va;
      float vb = (gk < 1024) ? Why_w[(long)(col0 + r) * 1024 + gk]
                             : Wry_w[(long)(col0 + r) * 256 + gk - 1024];
      bl[k * 132 + r] = vb;
    }
    __syncthreads();
#pragma unroll
    for (int k = 0; k < 16; ++k) {
      float4 a0 = *(const float4*)&al[k * 132 + ty * 8];
      float4 a1 = *(const float4*)&al[k * 132 + ty * 8 + 4];
      float4 c0 = *(const float4*)&bl[k * 132 + tx * 4];
      float4 c1 = *(const float4*)&bl[k * 132 + 64 + tx * 4];
      float ar[8] = {a0.x, a0.y, a0.z, a0.w, a1.x, a1.y, a1.z, a1.w};
      float br[8] = {c0.x, c0.y, c0.z, c0.w, c1.x, c1.y, c1.z, c1.w};
#pragma unroll
      for (int i = 0; i < 8; ++i)
#pragma unroll
        for (int j = 0; j < 8; ++j) acc[i][j] += ar[i] * br[j];
    }
  }
  float4 bb0 = *(const float4*)&Why_b[col0 + tx * 4];
  float4 bb1 = *(const float4*)&Why_b[col0 + 64 + tx * 4];
  float bias[8] = {bb0.x, bb0.y, bb0.z, bb0.w, bb1.x, bb1.y, bb1.z, bb1.w};
#pragma unroll
  for (int i = 0; i < 8; ++i) {
    long r = row0 + ty * 8 + i;
    float* op0 = out + r * 16000 + col0 + tx * 4;
    float* op1 = out + r * 16000 + col0 + 64 + tx * 4;
    float4 o0 = {acc[i][0] + bias[0], acc[i][1] + bias[1], acc[i][2] + bias[2], acc[i][3] + bias[3]};
    float4 o1 = {acc[i][4] + bias[4], acc[i][5] + bias[5], acc[i][6] + bias[6], acc[i][7] + bias[7]};
    *(float4*)op0 = o0;
    *(float4*)op1 = o1;
  }
}

extern "C" void kernel_launch(void* const* d_in, const int* in_sizes, int n_in,
                              void* d_out, int out_size, void* d_ws, size_t ws_size,
                              hipStream_t stream) {
  const void* src_raw = d_in[0];
  const float* emb   = (const float*)d_in[1];
  const float* W_ih  = (const float*)d_in[2];
  const float* W_hh  = (const float*)d_in[3];
  const float* b_ih  = (const float*)d_in[4];
  const float* b_hh  = (const float*)d_in[5];
  const float* rk_w  = (const float*)d_in[6];
  const float* rk_b  = (const float*)d_in[7];
  const float* rs_w  = (const float*)d_in[8];
  const float* rs_b  = (const float*)d_in[9];
  const float* fg_w  = (const float*)d_in[10];
  const float* fg_b  = (const float*)d_in[11];
  const float* rm_w  = (const float*)d_in[12];
  const float* rm_b  = (const float*)d_in[13];
  const float* wk_w  = (const float*)d_in[14];
  const float* wk_b  = (const float*)d_in[15];
  const float* ws_w  = (const float*)d_in[16];
  const float* ws_b  = (const float*)d_in[17];
  const float* ev_w  = (const float*)d_in[18];
  const float* ev_b  = (const float*)d_in[19];
  const float* wv_w  = (const float*)d_in[20];
  const float* wv_b  = (const float*)d_in[21];
  const float* ag_w  = (const float*)d_in[22];
  const float* ag_b  = (const float*)d_in[23];
  const float* wg_w  = (const float*)d_in[24];
  const float* wg_b  = (const float*)d_in[25];
  const float* Why_w = (const float*)d_in[26];
  const float* Why_b = (const float*)d_in[27];
  const float* Wry_w = (const float*)d_in[28];
  float* ws = (float*)d_ws;
  float* out = (float*)d_out;

  src_decode<<<1, 256, 0, stream>>>(src_raw, ws);
  init_kernel<<<512, 256, 0, stream>>>(ws);
  const size_t smem_bytes = (size_t)SMEMF * sizeof(float);  // ~116 KB
  for (int t = 0; t < TN; ++t) {
    gates4_kernel<<<128, 256, 0, stream>>>(t, emb, W_ih, W_hh, b_ih, b_hh, ws);
    proj_kernel<<<dim3(30, 4), 256, 0, stream>>>(t, ws, rk_w, rk_b, rs_w, rs_b, fg_w, fg_b,
                                                 rm_w, rm_b, wk_w, wk_b, ws_w, ws_b,
                                                 ev_w, ev_b, wv_w, wv_b, ag_w, ag_b, wg_w, wg_b);
    memAB_kernel<<<32, 256, smem_bytes, stream>>>(t, ws);
  }
  out_gemm<<<dim3(125, 16), 256, 0, stream>>>(ws, Why_w, Why_b, Wry_w, out);
}